// Round 1
// baseline (176.962 us; speedup 1.0000x reference)
//
#include <hip/hip_runtime.h>
#include <hip/hip_bf16.h>
#include <math.h>
#include <cstdint>

// Problem constants
#define NUSER 16384   // B*U
#define NSRV  4096    // B*S
#define BB    64
#define UU    256
#define SSLOT 64
#define HD    256
#define DEGS  8
#define DEGU  16

// ---------------------------------------------------------------------------
// K1: per-user connection bitmasks (dedupes duplicate edges; .set semantics)
// ---------------------------------------------------------------------------
__global__ __launch_bounds__(256) void k_masks(
    const int* __restrict__ dst_u2s, const int* __restrict__ dst_u2u,
    unsigned long long* __restrict__ connS, unsigned long long* __restrict__ connU) {
  int u = blockIdx.x * blockDim.x + threadIdx.x;
  if (u >= NUSER) return;
  unsigned long long ms = 0ull;
  #pragma unroll
  for (int i = 0; i < DEGS; ++i) {
    int slot = dst_u2s[u * DEGS + i] & 63;
    ms |= (1ull << slot);
  }
  connS[u] = ms;
  unsigned long long m0 = 0, m1 = 0, m2 = 0, m3 = 0;
  #pragma unroll
  for (int i = 0; i < DEGU; ++i) {
    int slot = dst_u2u[u * DEGU + i] & 255;
    unsigned long long bit = 1ull << (slot & 63);
    int w = slot >> 6;
    if (w == 0) m0 |= bit; else if (w == 1) m1 |= bit; else if (w == 2) m2 |= bit; else m3 |= bit;
  }
  connU[u * 4 + 0] = m0; connU[u * 4 + 1] = m1;
  connU[u * 4 + 2] = m2; connU[u * 4 + 3] = m3;
}

// ---------------------------------------------------------------------------
// K2: P[g] = x_server[g] . W1[slot*16 : +16, :]  (server part, rows 0..1023)
//     Q[g] = x_user[g]   . W1[1024 + slot*16 : +16, :]
// One WG per slot; loops over the 64 batches. Weights read once total.
// ---------------------------------------------------------------------------
__global__ __launch_bounds__(256) void k_pq(
    const float* __restrict__ xu, const float* __restrict__ xs,
    const float* __restrict__ oW1, const float* __restrict__ sW1,
    float* __restrict__ P_o, float* __restrict__ P_s,
    float* __restrict__ Q_o, float* __restrict__ Q_s) {
  const int t = threadIdx.x;            // h column
  const int wg = blockIdx.x;            // 0..63 server slots, 64..319 user slots
  __shared__ float lx[BB * 16];
  if (wg < SSLOT) {
    const int s = wg;
    for (int i = t; i < BB * 16; i += 256) {
      int b = i >> 4, d = i & 15;
      lx[i] = xs[(b * SSLOT + s) * 16 + d];
    }
    __syncthreads();
    float wo[16], wsv[16];
    #pragma unroll
    for (int d = 0; d < 16; ++d) {
      int row = s * 16 + d;
      wo[d] = oW1[row * HD + t];
      wsv[d] = sW1[row * HD + t];
    }
    for (int b = 0; b < BB; ++b) {
      float ao = 0.f, as = 0.f;
      #pragma unroll
      for (int d = 0; d < 16; ++d) {
        float f = lx[b * 16 + d];
        ao = fmaf(f, wo[d], ao);
        as = fmaf(f, wsv[d], as);
      }
      P_o[(b * SSLOT + s) * HD + t] = ao;
      P_s[(b * SSLOT + s) * HD + t] = as;
    }
  } else {
    const int v = wg - SSLOT;
    for (int i = t; i < BB * 16; i += 256) {
      int b = i >> 4, d = i & 15;
      lx[i] = xu[(b * UU + v) * 16 + d];
    }
    __syncthreads();
    float wo[16], wsv[16];
    #pragma unroll
    for (int d = 0; d < 16; ++d) {
      int row = SSLOT * 16 + v * 16 + d;   // 1024 + v*16 + d
      wo[d] = oW1[row * HD + t];
      wsv[d] = sW1[row * HD + t];
    }
    for (int b = 0; b < BB; ++b) {
      float ao = 0.f, as = 0.f;
      #pragma unroll
      for (int d = 0; d < 16; ++d) {
        float f = lx[b * 16 + d];
        ao = fmaf(f, wo[d], ao);
        as = fmaf(f, wsv[d], as);
      }
      Q_o[(b * UU + v) * HD + t] = ao;
      Q_s[(b * UU + v) * HD + t] = as;
    }
  }
}

// ---------------------------------------------------------------------------
// K3: h1 = relu(b1 + sum_{connected s} P[s] + sum_{connected v} Q[v])
// One WG (256 thr) per user; masks are wave-uniform.
// ---------------------------------------------------------------------------
__global__ __launch_bounds__(256) void k_h1(
    const unsigned long long* __restrict__ connS,
    const unsigned long long* __restrict__ connU,
    const float* __restrict__ P_o, const float* __restrict__ P_s,
    const float* __restrict__ Q_o, const float* __restrict__ Q_s,
    const float* __restrict__ ob1, const float* __restrict__ sb1,
    float* __restrict__ h1o, float* __restrict__ h1s) {
  const int u = blockIdx.x;
  const int t = threadIdx.x;
  const int b = u >> 8;
  float ao = ob1[t], as = sb1[t];
  unsigned long long ms = connS[u];
  while (ms) {
    int s = __ffsll((unsigned long long)ms) - 1;
    ms &= ms - 1;
    int g = (b * SSLOT + s) * HD + t;
    ao += P_o[g];
    as += P_s[g];
  }
  #pragma unroll
  for (int w = 0; w < 4; ++w) {
    unsigned long long mu = connU[u * 4 + w];
    while (mu) {
      int v = (w << 6) + __ffsll((unsigned long long)mu) - 1;
      mu &= mu - 1;
      int g = (b * UU + v) * HD + t;
      ao += Q_o[g];
      as += Q_s[g];
    }
  }
  h1o[u * HD + t] = fmaxf(ao, 0.f);
  h1s[u * HD + t] = fmaxf(as, 0.f);
}

// ---------------------------------------------------------------------------
// K4: in-place h2 = sigmoid(h1 @ W2 + b2), per-MLP via blockIdx.y.
// Tile: 64 users x 256 cols per WG; k-tiles of 32; 8x8 register micro-tile.
// ---------------------------------------------------------------------------
__global__ __launch_bounds__(256) void k_gemm_h2(
    float* __restrict__ h1o, float* __restrict__ h1s,
    const float* __restrict__ oW2, const float* __restrict__ ob2,
    const float* __restrict__ sW2, const float* __restrict__ sb2) {
  float* A = blockIdx.y ? h1s : h1o;
  const float* W = blockIdx.y ? sW2 : oW2;
  const float* bias = blockIdx.y ? sb2 : ob2;
  const int u0 = blockIdx.x * 64;
  const int t = threadIdx.x;
  const int tu = t >> 5, th = t & 31;
  __shared__ float AsT[32 * 68];   // [k][u] padded stride 68
  __shared__ float Bs[32 * 256];   // [k][n]
  float acc[8][8] = {};
  for (int kt = 0; kt < 8; ++kt) {
    const int k0 = kt * 32;
    #pragma unroll
    for (int r = 0; r < 8; ++r) {
      int idx = t + 256 * r;
      int au = idx >> 5, ak = idx & 31;
      AsT[ak * 68 + au] = A[(u0 + au) * HD + k0 + ak];
    }
    #pragma unroll
    for (int r = 0; r < 32; ++r) {
      Bs[r * 256 + t] = W[(k0 + r) * HD + t];
    }
    __syncthreads();
    #pragma unroll
    for (int k = 0; k < 32; ++k) {
      float4 a0 = *(const float4*)&AsT[k * 68 + tu * 8];
      float4 a1 = *(const float4*)&AsT[k * 68 + tu * 8 + 4];
      float4 b0 = *(const float4*)&Bs[k * 256 + th * 8];
      float4 b1 = *(const float4*)&Bs[k * 256 + th * 8 + 4];
      float av[8], bv[8];
      av[0]=a0.x; av[1]=a0.y; av[2]=a0.z; av[3]=a0.w;
      av[4]=a1.x; av[5]=a1.y; av[6]=a1.z; av[7]=a1.w;
      bv[0]=b0.x; bv[1]=b0.y; bv[2]=b0.z; bv[3]=b0.w;
      bv[4]=b1.x; bv[5]=b1.y; bv[6]=b1.z; bv[7]=b1.w;
      #pragma unroll
      for (int i = 0; i < 8; ++i)
        #pragma unroll
        for (int j = 0; j < 8; ++j)
          acc[i][j] = fmaf(av[i], bv[j], acc[i][j]);
    }
    __syncthreads();
  }
  #pragma unroll
  for (int i = 0; i < 8; ++i) {
    int u = u0 + tu * 8 + i;
    #pragma unroll
    for (int j = 0; j < 8; ++j) {
      int n = th * 8 + j;
      float x = acc[i][j] + bias[n];
      A[u * HD + n] = 1.0f / (1.0f + __expf(-x));
    }
  }
}

// ---------------------------------------------------------------------------
// K5: sel logits = h2s @ sW3 + sb3  -> [NUSER, 64]
// Tile 64 users x 64 cols; k-tiles of 64; 4x4 micro-tile.
// ---------------------------------------------------------------------------
__global__ __launch_bounds__(256) void k_gemm_s3(
    const float* __restrict__ h2s, const float* __restrict__ sW3,
    const float* __restrict__ sb3, float* __restrict__ lg) {
  const int u0 = blockIdx.x * 64;
  const int t = threadIdx.x;
  const int tu = t >> 4, tn = t & 15;
  __shared__ float AsT[64 * 68];
  __shared__ float Bs[64 * 64];
  float acc[4][4] = {};
  for (int kt = 0; kt < 4; ++kt) {
    const int k0 = kt * 64;
    #pragma unroll
    for (int r = 0; r < 16; ++r) {
      int idx = t + 256 * r;
      int au = idx >> 6, ak = idx & 63;
      AsT[ak * 68 + au] = h2s[(u0 + au) * HD + k0 + ak];
    }
    #pragma unroll
    for (int r = 0; r < 16; ++r) {
      int idx = t + 256 * r;
      int bk = idx >> 6, bn = idx & 63;
      Bs[bk * 64 + bn] = sW3[(k0 + bk) * SSLOT + bn];
    }
    __syncthreads();
    #pragma unroll
    for (int k = 0; k < 64; ++k) {
      float4 a = *(const float4*)&AsT[k * 68 + tu * 4];
      float4 b = *(const float4*)&Bs[k * 64 + tn * 4];
      float av[4] = {a.x, a.y, a.z, a.w};
      float bv[4] = {b.x, b.y, b.z, b.w};
      #pragma unroll
      for (int i = 0; i < 4; ++i)
        #pragma unroll
        for (int j = 0; j < 4; ++j)
          acc[i][j] = fmaf(av[i], bv[j], acc[i][j]);
    }
    __syncthreads();
  }
  #pragma unroll
  for (int i = 0; i < 4; ++i)
    #pragma unroll
    for (int j = 0; j < 4; ++j)
      lg[(u0 + tu * 4 + i) * SSLOT + tn * 4 + j] = acc[i][j] + sb3[tn * 4 + j];
}

// ---------------------------------------------------------------------------
// K6: offloading logits (H->2) + softmax2; masked softmax over sel logits.
// 4 users per WG, one 64-lane wave per user.
// ---------------------------------------------------------------------------
__global__ __launch_bounds__(256) void k_final(
    const float* __restrict__ h2o, const float* __restrict__ lg,
    const unsigned long long* __restrict__ connS,
    const float* __restrict__ oW3, const float* __restrict__ ob3,
    float* __restrict__ out) {
  const int lane = threadIdx.x & 63;
  const int usub = threadIdx.x >> 6;
  const int u = blockIdx.x * 4 + usub;
  // --- offloading head ---
  float p0 = 0.f, p1 = 0.f;
  #pragma unroll
  for (int it = 0; it < 4; ++it) {
    int k = lane + it * 64;
    float h = h2o[u * HD + k];
    p0 = fmaf(h, oW3[k * 2 + 0], p0);
    p1 = fmaf(h, oW3[k * 2 + 1], p1);
  }
  #pragma unroll
  for (int off = 32; off > 0; off >>= 1) {
    p0 += __shfl_xor(p0, off, 64);
    p1 += __shfl_xor(p1, off, 64);
  }
  p0 += ob3[0];
  p1 += ob3[1];
  float m2 = fmaxf(p0, p1);
  float e0 = __expf(p0 - m2), e1 = __expf(p1 - m2);
  float inv2 = 1.f / (e0 + e1);
  if (lane == 0) {
    out[u * 2 + 0] = e0 * inv2;
    out[u * 2 + 1] = e1 * inv2;
  }
  // --- selection head (masked softmax over 64 slots) ---
  unsigned long long msk = connS[u];
  bool conn = (msk >> lane) & 1ull;
  float lgv = conn ? lg[u * SSLOT + lane] : -INFINITY;
  float mx = lgv;
  #pragma unroll
  for (int off = 32; off > 0; off >>= 1) mx = fmaxf(mx, __shfl_xor(mx, off, 64));
  float e = conn ? __expf(lgv - mx) : 0.f;
  float s = e;
  #pragma unroll
  for (int off = 32; off > 0; off >>= 1) s += __shfl_xor(s, off, 64);
  out[NUSER * 2 + u * SSLOT + lane] = e / s;
}

// ---------------------------------------------------------------------------
extern "C" void kernel_launch(void* const* d_in, const int* in_sizes, int n_in,
                              void* d_out, int out_size, void* d_ws, size_t ws_size,
                              hipStream_t stream) {
  const float* x_user   = (const float*)d_in[0];
  const float* x_server = (const float*)d_in[1];
  const int*   dst_u2s  = (const int*)d_in[3];
  const int*   dst_u2u  = (const int*)d_in[5];
  const float* oW1 = (const float*)d_in[6];
  const float* ob1 = (const float*)d_in[7];
  const float* oW2 = (const float*)d_in[8];
  const float* ob2 = (const float*)d_in[9];
  const float* oW3 = (const float*)d_in[10];
  const float* ob3 = (const float*)d_in[11];
  const float* sW1 = (const float*)d_in[12];
  const float* sb1 = (const float*)d_in[13];
  const float* sW2 = (const float*)d_in[14];
  const float* sb2 = (const float*)d_in[15];
  const float* sW3 = (const float*)d_in[16];
  const float* sb3 = (const float*)d_in[17];

  char* ws = (char*)d_ws;
  unsigned long long* connS = (unsigned long long*)(ws + 0);
  unsigned long long* connU = (unsigned long long*)(ws + 131072);
  float* P_o = (float*)(ws + 655360);
  float* P_s = (float*)(ws + 4849664);
  float* Q_o = (float*)(ws + 9043968);
  float* Q_s = (float*)(ws + 25821184);
  float* h1o = (float*)(ws + 42598400);   // becomes h2o in-place after K4
  float* h1s = (float*)(ws + 59375616);   // becomes h2s in-place after K4
  float* lg  = (float*)(ws + 76152832);
  float* out = (float*)d_out;

  k_masks<<<NUSER / 256, 256, 0, stream>>>(dst_u2s, dst_u2u, connS, connU);
  k_pq<<<SSLOT + UU, 256, 0, stream>>>(x_user, x_server, oW1, sW1, P_o, P_s, Q_o, Q_s);
  k_h1<<<NUSER, 256, 0, stream>>>(connS, connU, P_o, P_s, Q_o, Q_s, ob1, sb1, h1o, h1s);
  k_gemm_h2<<<dim3(NUSER / 64, 2), 256, 0, stream>>>(h1o, h1s, oW2, ob2, sW2, sb2);
  k_gemm_s3<<<NUSER / 64, 256, 0, stream>>>(h1s, sW3, sb3, lg);
  k_final<<<NUSER / 4, 256, 0, stream>>>(h1o, lg, connS, oW3, ob3, out);
}

// Round 2
// 104.871 us; speedup vs baseline: 1.6874x; 1.6874x over previous
//
#include <hip/hip_runtime.h>
#include <hip/hip_bf16.h>
#include <math.h>
#include <cstdint>

#define NUSER 16384   // B*U
#define BB    64
#define UU    256
#define SSLOT 64
#define HD    256
#define DEGS  8
#define DEGU  16

typedef __attribute__((ext_vector_type(8))) short short8;
typedef __attribute__((ext_vector_type(4))) float f32x4;

static __device__ __forceinline__ float b2f(__hip_bfloat16 x) { return __bfloat162float(x); }
static __device__ __forceinline__ __hip_bfloat16 f2b(float x) { return __float2bfloat16(x); }

// ---------------------------------------------------------------------------
// K0: connection bitmasks + weight transposes to bf16 (W2T[n][k], W3T[n][k]).
// grid 256x256: block b transposes W2 row n=b; blocks 0..63 also do masks+W3T.
// ---------------------------------------------------------------------------
__global__ __launch_bounds__(256) void k_setup(
    const int* __restrict__ dst_u2s, const int* __restrict__ dst_u2u,
    const float* __restrict__ oW2, const float* __restrict__ sW2,
    const float* __restrict__ sW3,
    unsigned long long* __restrict__ connS, unsigned long long* __restrict__ connU,
    __hip_bfloat16* __restrict__ W2T_o, __hip_bfloat16* __restrict__ W2T_s,
    __hip_bfloat16* __restrict__ W3T_s) {
  const int b = blockIdx.x, t = threadIdx.x;
  W2T_o[b * HD + t] = f2b(oW2[t * HD + b]);
  W2T_s[b * HD + t] = f2b(sW2[t * HD + b]);
  if (b < SSLOT) W3T_s[b * HD + t] = f2b(sW3[t * SSLOT + b]);
  if (b < NUSER / 256) {
    const int u = b * 256 + t;
    unsigned long long ms = 0ull;
    #pragma unroll
    for (int i = 0; i < DEGS; ++i) ms |= 1ull << (dst_u2s[u * DEGS + i] & 63);
    connS[u] = ms;
    unsigned long long m0 = 0, m1 = 0, m2 = 0, m3 = 0;
    #pragma unroll
    for (int i = 0; i < DEGU; ++i) {
      int slot = dst_u2u[u * DEGU + i] & 255;
      unsigned long long bit = 1ull << (slot & 63);
      int w = slot >> 6;
      if (w == 0) m0 |= bit; else if (w == 1) m1 |= bit; else if (w == 2) m2 |= bit; else m3 |= bit;
    }
    connU[u * 4 + 0] = m0; connU[u * 4 + 1] = m1;
    connU[u * 4 + 2] = m2; connU[u * 4 + 3] = m3;
  }
}

// ---------------------------------------------------------------------------
// K1: per-slot partial layer-1 products, stored bf16.
// P[g] = x_server[g] . W1[slot*16:+16, :]; Q[g] = x_user[g] . W1[1024+v*16:+16,:]
// ---------------------------------------------------------------------------
__global__ __launch_bounds__(256) void k_pq(
    const float* __restrict__ xu, const float* __restrict__ xs,
    const float* __restrict__ oW1, const float* __restrict__ sW1,
    __hip_bfloat16* __restrict__ P_o, __hip_bfloat16* __restrict__ P_s,
    __hip_bfloat16* __restrict__ Q_o, __hip_bfloat16* __restrict__ Q_s) {
  const int t = threadIdx.x;            // h column
  const int wg = blockIdx.x;            // 0..63 server slots, 64..319 user slots
  __shared__ float lx[BB * 16];
  if (wg < SSLOT) {
    const int s = wg;
    for (int i = t; i < BB * 16; i += 256) {
      int b = i >> 4, d = i & 15;
      lx[i] = xs[(b * SSLOT + s) * 16 + d];
    }
    __syncthreads();
    float wo[16], wsv[16];
    #pragma unroll
    for (int d = 0; d < 16; ++d) {
      int row = s * 16 + d;
      wo[d] = oW1[row * HD + t];
      wsv[d] = sW1[row * HD + t];
    }
    for (int b = 0; b < BB; ++b) {
      float ao = 0.f, as = 0.f;
      #pragma unroll
      for (int d = 0; d < 16; ++d) {
        float f = lx[b * 16 + d];
        ao = fmaf(f, wo[d], ao);
        as = fmaf(f, wsv[d], as);
      }
      P_o[(b * SSLOT + s) * HD + t] = f2b(ao);
      P_s[(b * SSLOT + s) * HD + t] = f2b(as);
    }
  } else {
    const int v = wg - SSLOT;
    for (int i = t; i < BB * 16; i += 256) {
      int b = i >> 4, d = i & 15;
      lx[i] = xu[(b * UU + v) * 16 + d];
    }
    __syncthreads();
    float wo[16], wsv[16];
    #pragma unroll
    for (int d = 0; d < 16; ++d) {
      int row = SSLOT * 16 + v * 16 + d;
      wo[d] = oW1[row * HD + t];
      wsv[d] = sW1[row * HD + t];
    }
    for (int b = 0; b < BB; ++b) {
      float ao = 0.f, as = 0.f;
      #pragma unroll
      for (int d = 0; d < 16; ++d) {
        float f = lx[b * 16 + d];
        ao = fmaf(f, wo[d], ao);
        as = fmaf(f, wsv[d], as);
      }
      Q_o[(b * UU + v) * HD + t] = f2b(ao);
      Q_s[(b * UU + v) * HD + t] = f2b(as);
    }
  }
}

// ---------------------------------------------------------------------------
// K2: h1 = relu(b1 + sum connected P + sum connected Q), bf16 in/out.
// XCD-affinity swizzle: XCD x owns batches with b%8==x-chunk (m204 bijective).
// ---------------------------------------------------------------------------
__global__ __launch_bounds__(256) void k_h1(
    const unsigned long long* __restrict__ connS,
    const unsigned long long* __restrict__ connU,
    const __hip_bfloat16* __restrict__ P_o, const __hip_bfloat16* __restrict__ P_s,
    const __hip_bfloat16* __restrict__ Q_o, const __hip_bfloat16* __restrict__ Q_s,
    const float* __restrict__ ob1, const float* __restrict__ sb1,
    __hip_bfloat16* __restrict__ h1o, __hip_bfloat16* __restrict__ h1s) {
  const int orig = blockIdx.x;
  const int u = (orig & 7) * (NUSER / 8) + (orig >> 3);   // contiguous chunk per XCD
  const int t = threadIdx.x;
  const int b = u >> 8;
  float ao = ob1[t], as = sb1[t];
  unsigned long long ms = connS[u];
  while (ms) {
    int s = __ffsll(ms) - 1;
    ms &= ms - 1;
    int g = (b * SSLOT + s) * HD + t;
    ao += b2f(P_o[g]);
    as += b2f(P_s[g]);
  }
  #pragma unroll
  for (int w = 0; w < 4; ++w) {
    unsigned long long mu = connU[u * 4 + w];
    while (mu) {
      int v = (w << 6) + __ffsll(mu) - 1;
      mu &= mu - 1;
      int g = (b * UU + v) * HD + t;
      ao += b2f(Q_o[g]);
      as += b2f(Q_s[g]);
    }
  }
  h1o[u * HD + t] = f2b(fmaxf(ao, 0.f));
  h1s[u * HD + t] = f2b(fmaxf(as, 0.f));
}

// ---------------------------------------------------------------------------
// K3: h2 = sigmoid(h1 @ W2 + b2) via bf16 MFMA. Out-of-place, bf16 out.
// grid (M/128, N/128=2, MLP=2); 4 waves/WG, wave tile 64x64 (4x4 frags).
// LDS tiles [128 rows][64 k] bf16, XOR-swizzled chunk^=(row&7).
// ---------------------------------------------------------------------------
__global__ __launch_bounds__(256) void k_h2(
    const __hip_bfloat16* __restrict__ h1o, const __hip_bfloat16* __restrict__ h1s,
    const __hip_bfloat16* __restrict__ W2T_o, const __hip_bfloat16* __restrict__ W2T_s,
    const float* __restrict__ ob2, const float* __restrict__ sb2,
    __hip_bfloat16* __restrict__ h2o, __hip_bfloat16* __restrict__ h2s) {
  const __hip_bfloat16* A  = blockIdx.z ? h1s : h1o;
  const __hip_bfloat16* BT = blockIdx.z ? W2T_s : W2T_o;
  const float* bias        = blockIdx.z ? sb2 : ob2;
  __hip_bfloat16* OUT      = blockIdx.z ? h2s : h2o;
  const int u0 = blockIdx.x * 128;
  const int n0 = blockIdx.y * 128;
  const int t = threadIdx.x;
  const int lane = t & 63;
  const int wr = (t >> 6) >> 1, wc = (t >> 6) & 1;
  __shared__ short As[128 * 64];
  __shared__ short Bs[128 * 64];
  f32x4 acc[4][4] = {};
  for (int kt = 0; kt < 4; ++kt) {
    const int kb = kt * 64;
    #pragma unroll
    for (int i = 0; i < 4; ++i) {                 // 1024 16B chunks per matrix
      int c = t + i * 256;
      int row = c >> 3, cc = c & 7;
      int sc = cc ^ (row & 7);
      *(short8*)&As[row * 64 + sc * 8] =
          *(const short8*)(A + (u0 + row) * HD + kb + cc * 8);
      *(short8*)&Bs[row * 64 + sc * 8] =
          *(const short8*)(BT + (n0 + row) * HD + kb + cc * 8);
    }
    __syncthreads();
    #pragma unroll
    for (int ks = 0; ks < 2; ++ks) {
      short8 af[4], bf[4];
      #pragma unroll
      for (int rb = 0; rb < 4; ++rb) {
        int row = wr * 64 + rb * 16 + (lane & 15);
        int c = ks * 4 + (lane >> 4);
        af[rb] = *(const short8*)&As[row * 64 + (c ^ (row & 7)) * 8];
      }
      #pragma unroll
      for (int cb = 0; cb < 4; ++cb) {
        int rn = wc * 64 + cb * 16 + (lane & 15);
        int c = ks * 4 + (lane >> 4);
        bf[cb] = *(const short8*)&Bs[rn * 64 + (c ^ (rn & 7)) * 8];
      }
      #pragma unroll
      for (int rb = 0; rb < 4; ++rb)
        #pragma unroll
        for (int cb = 0; cb < 4; ++cb)
          acc[rb][cb] = __builtin_amdgcn_mfma_f32_16x16x32_bf16(af[rb], bf[cb], acc[rb][cb], 0, 0, 0);
    }
    __syncthreads();
  }
  #pragma unroll
  for (int rb = 0; rb < 4; ++rb)
    #pragma unroll
    for (int cb = 0; cb < 4; ++cb) {
      int n = n0 + wc * 64 + cb * 16 + (lane & 15);
      float bs = bias[n];
      #pragma unroll
      for (int j = 0; j < 4; ++j) {
        int u = u0 + wr * 64 + rb * 16 + (lane >> 4) * 4 + j;
        float x = acc[rb][cb][j] + bs;
        OUT[u * HD + n] = f2b(1.0f / (1.0f + __expf(-x)));
      }
    }
}

// ---------------------------------------------------------------------------
// K4: sel logits = h2s @ sW3 + sb3 -> f32 [NUSER,64], bf16 MFMA.
// grid M/256; 4 waves, each 64 users x 64 cols.
// ---------------------------------------------------------------------------
__global__ __launch_bounds__(256) void k_s3(
    const __hip_bfloat16* __restrict__ h2s, const __hip_bfloat16* __restrict__ W3T_s,
    const float* __restrict__ sb3, float* __restrict__ lg) {
  const int u0 = blockIdx.x * 256;
  const int t = threadIdx.x;
  const int lane = t & 63;
  const int w = t >> 6;
  __shared__ short As[256 * 64];
  __shared__ short Bs[64 * 64];
  f32x4 acc[4][4] = {};
  for (int kt = 0; kt < 4; ++kt) {
    const int kb = kt * 64;
    #pragma unroll
    for (int i = 0; i < 8; ++i) {                 // A: 2048 chunks
      int c = t + i * 256;
      int row = c >> 3, cc = c & 7;
      int sc = cc ^ (row & 7);
      *(short8*)&As[row * 64 + sc * 8] =
          *(const short8*)(h2s + (u0 + row) * HD + kb + cc * 8);
    }
    #pragma unroll
    for (int i = 0; i < 2; ++i) {                 // B: 512 chunks
      int c = t + i * 256;
      int row = c >> 3, cc = c & 7;
      int sc = cc ^ (row & 7);
      *(short8*)&Bs[row * 64 + sc * 8] =
          *(const short8*)(W3T_s + row * HD + kb + cc * 8);
    }
    __syncthreads();
    #pragma unroll
    for (int ks = 0; ks < 2; ++ks) {
      short8 af[4], bf[4];
      #pragma unroll
      for (int rb = 0; rb < 4; ++rb) {
        int row = w * 64 + rb * 16 + (lane & 15);
        int c = ks * 4 + (lane >> 4);
        af[rb] = *(const short8*)&As[row * 64 + (c ^ (row & 7)) * 8];
      }
      #pragma unroll
      for (int cb = 0; cb < 4; ++cb) {
        int rn = cb * 16 + (lane & 15);
        int c = ks * 4 + (lane >> 4);
        bf[cb] = *(const short8*)&Bs[rn * 64 + (c ^ (rn & 7)) * 8];
      }
      #pragma unroll
      for (int rb = 0; rb < 4; ++rb)
        #pragma unroll
        for (int cb = 0; cb < 4; ++cb)
          acc[rb][cb] = __builtin_amdgcn_mfma_f32_16x16x32_bf16(af[rb], bf[cb], acc[rb][cb], 0, 0, 0);
    }
    __syncthreads();
  }
  #pragma unroll
  for (int rb = 0; rb < 4; ++rb)
    #pragma unroll
    for (int cb = 0; cb < 4; ++cb) {
      int n = cb * 16 + (lane & 15);
      float bs = sb3[n];
      #pragma unroll
      for (int j = 0; j < 4; ++j) {
        int u = u0 + w * 64 + rb * 16 + (lane >> 4) * 4 + j;
        lg[u * SSLOT + n] = acc[rb][cb][j] + bs;
      }
    }
}

// ---------------------------------------------------------------------------
// K5: offloading head (H->2) + softmax2; masked softmax over sel logits.
// ---------------------------------------------------------------------------
__global__ __launch_bounds__(256) void k_final(
    const __hip_bfloat16* __restrict__ h2o, const float* __restrict__ lg,
    const unsigned long long* __restrict__ connS,
    const float* __restrict__ oW3, const float* __restrict__ ob3,
    float* __restrict__ out) {
  const int lane = threadIdx.x & 63;
  const int usub = threadIdx.x >> 6;
  const int u = blockIdx.x * 4 + usub;
  float p0 = 0.f, p1 = 0.f;
  #pragma unroll
  for (int it = 0; it < 4; ++it) {
    int k = lane + it * 64;
    float h = b2f(h2o[u * HD + k]);
    p0 = fmaf(h, oW3[k * 2 + 0], p0);
    p1 = fmaf(h, oW3[k * 2 + 1], p1);
  }
  #pragma unroll
  for (int off = 32; off > 0; off >>= 1) {
    p0 += __shfl_xor(p0, off, 64);
    p1 += __shfl_xor(p1, off, 64);
  }
  p0 += ob3[0];
  p1 += ob3[1];
  float m2 = fmaxf(p0, p1);
  float e0 = __expf(p0 - m2), e1 = __expf(p1 - m2);
  float inv2 = 1.f / (e0 + e1);
  if (lane == 0) {
    out[u * 2 + 0] = e0 * inv2;
    out[u * 2 + 1] = e1 * inv2;
  }
  unsigned long long msk = connS[u];
  bool conn = (msk >> lane) & 1ull;
  float lgv = conn ? lg[u * SSLOT + lane] : -INFINITY;
  float mx = lgv;
  #pragma unroll
  for (int off = 32; off > 0; off >>= 1) mx = fmaxf(mx, __shfl_xor(mx, off, 64));
  float e = conn ? __expf(lgv - mx) : 0.f;
  float s = e;
  #pragma unroll
  for (int off = 32; off > 0; off >>= 1) s += __shfl_xor(s, off, 64);
  out[NUSER * 2 + u * SSLOT + lane] = e / s;
}

// ---------------------------------------------------------------------------
extern "C" void kernel_launch(void* const* d_in, const int* in_sizes, int n_in,
                              void* d_out, int out_size, void* d_ws, size_t ws_size,
                              hipStream_t stream) {
  const float* x_user   = (const float*)d_in[0];
  const float* x_server = (const float*)d_in[1];
  const int*   dst_u2s  = (const int*)d_in[3];
  const int*   dst_u2u  = (const int*)d_in[5];
  const float* oW1 = (const float*)d_in[6];
  const float* ob1 = (const float*)d_in[7];
  const float* oW2 = (const float*)d_in[8];
  const float* ob2 = (const float*)d_in[9];
  const float* oW3 = (const float*)d_in[10];
  const float* ob3 = (const float*)d_in[11];
  const float* sW1 = (const float*)d_in[12];
  const float* sb1 = (const float*)d_in[13];
  const float* sW2 = (const float*)d_in[14];
  const float* sb2 = (const float*)d_in[15];
  const float* sW3 = (const float*)d_in[16];
  const float* sb3 = (const float*)d_in[17];

  char* ws = (char*)d_ws;
  unsigned long long* connS = (unsigned long long*)(ws + 0);
  unsigned long long* connU = (unsigned long long*)(ws + 131072);
  __hip_bfloat16* P_o  = (__hip_bfloat16*)(ws + 655360);
  __hip_bfloat16* P_s  = (__hip_bfloat16*)(ws + 2752512);
  __hip_bfloat16* Q_o  = (__hip_bfloat16*)(ws + 4849664);
  __hip_bfloat16* Q_s  = (__hip_bfloat16*)(ws + 13238272);
  __hip_bfloat16* h1o  = (__hip_bfloat16*)(ws + 21626880);
  __hip_bfloat16* h1s  = (__hip_bfloat16*)(ws + 30015488);
  __hip_bfloat16* h2o  = (__hip_bfloat16*)(ws + 38404096);
  __hip_bfloat16* h2s  = (__hip_bfloat16*)(ws + 46792704);
  float*          lg   = (float*)(ws + 55181312);
  __hip_bfloat16* W2T_o = (__hip_bfloat16*)(ws + 59375616);
  __hip_bfloat16* W2T_s = (__hip_bfloat16*)(ws + 59506688);
  __hip_bfloat16* W3T_s = (__hip_bfloat16*)(ws + 59637760);
  float* out = (float*)d_out;

  k_setup<<<256, 256, 0, stream>>>(dst_u2s, dst_u2u, oW2, sW2, sW3,
                                   connS, connU, W2T_o, W2T_s, W3T_s);
  k_pq<<<SSLOT + UU, 256, 0, stream>>>(x_user, x_server, oW1, sW1, P_o, P_s, Q_o, Q_s);
  k_h1<<<NUSER, 256, 0, stream>>>(connS, connU, P_o, P_s, Q_o, Q_s, ob1, sb1, h1o, h1s);
  k_h2<<<dim3(NUSER / 128, 2, 2), 256, 0, stream>>>(h1o, h1s, W2T_o, W2T_s, ob2, sb2, h2o, h2s);
  k_s3<<<NUSER / 256, 256, 0, stream>>>(h2s, W3T_s, sb3, lg);
  k_final<<<NUSER / 4, 256, 0, stream>>>(h2o, lg, connS, oW3, ob3, out);
}

// Round 3
// 79.271 us; speedup vs baseline: 2.2324x; 1.3230x over previous
//
#include <hip/hip_runtime.h>
#include <hip/hip_bf16.h>
#include <math.h>
#include <cstdint>

#define NUSER 16384   // B*U
#define BB    64
#define UU    256
#define SSLOT 64
#define HD    256
#define DEGS  8
#define DEGU  16

typedef __attribute__((ext_vector_type(8))) short short8;
typedef __attribute__((ext_vector_type(4))) float f32x4;

static __device__ __forceinline__ float b2f(__hip_bfloat16 x) { return __bfloat162float(x); }
static __device__ __forceinline__ __hip_bfloat16 f2b(float x) { return __float2bfloat16(x); }
static __device__ __forceinline__ float uf(unsigned u) { return __uint_as_float(u); }
static __device__ __forceinline__ unsigned pack2(float x, float y) {
  union { __hip_bfloat16 h[2]; unsigned u; } cv;
  cv.h[0] = f2b(x); cv.h[1] = f2b(y);
  return cv.u;
}

// ---------------------------------------------------------------------------
// K0: connection bitmasks + weight transposes to bf16 (W2T[n][k], W3T[n][k]).
// ---------------------------------------------------------------------------
__global__ __launch_bounds__(256) void k_setup(
    const int* __restrict__ dst_u2s, const int* __restrict__ dst_u2u,
    const float* __restrict__ oW2, const float* __restrict__ sW2,
    const float* __restrict__ sW3,
    unsigned long long* __restrict__ connS, unsigned long long* __restrict__ connU,
    __hip_bfloat16* __restrict__ W2T_o, __hip_bfloat16* __restrict__ W2T_s,
    __hip_bfloat16* __restrict__ W3T_s) {
  const int b = blockIdx.x, t = threadIdx.x;
  W2T_o[b * HD + t] = f2b(oW2[t * HD + b]);
  W2T_s[b * HD + t] = f2b(sW2[t * HD + b]);
  if (b < SSLOT) W3T_s[b * HD + t] = f2b(sW3[t * SSLOT + b]);
  if (b < NUSER / 256) {
    const int u = b * 256 + t;
    unsigned long long ms = 0ull;
    #pragma unroll
    for (int i = 0; i < DEGS; ++i) ms |= 1ull << (dst_u2s[u * DEGS + i] & 63);
    connS[u] = ms;
    unsigned long long m0 = 0, m1 = 0, m2 = 0, m3 = 0;
    #pragma unroll
    for (int i = 0; i < DEGU; ++i) {
      int slot = dst_u2u[u * DEGU + i] & 255;
      unsigned long long bit = 1ull << (slot & 63);
      int w = slot >> 6;
      if (w == 0) m0 |= bit; else if (w == 1) m1 |= bit; else if (w == 2) m2 |= bit; else m3 |= bit;
    }
    connU[u * 4 + 0] = m0; connU[u * 4 + 1] = m1;
    connU[u * 4 + 2] = m2; connU[u * 4 + 3] = m3;
  }
}

// ---------------------------------------------------------------------------
// K1: per-slot partial layer-1 products, stored bf16.
// ---------------------------------------------------------------------------
__global__ __launch_bounds__(256) void k_pq(
    const float* __restrict__ xu, const float* __restrict__ xs,
    const float* __restrict__ oW1, const float* __restrict__ sW1,
    __hip_bfloat16* __restrict__ P_o, __hip_bfloat16* __restrict__ P_s,
    __hip_bfloat16* __restrict__ Q_o, __hip_bfloat16* __restrict__ Q_s) {
  const int t = threadIdx.x;
  const int wg = blockIdx.x;            // 0..63 server slots, 64..319 user slots
  __shared__ float lx[BB * 16];
  if (wg < SSLOT) {
    const int s = wg;
    for (int i = t; i < BB * 16; i += 256) {
      int b = i >> 4, d = i & 15;
      lx[i] = xs[(b * SSLOT + s) * 16 + d];
    }
    __syncthreads();
    float wo[16], wsv[16];
    #pragma unroll
    for (int d = 0; d < 16; ++d) {
      int row = s * 16 + d;
      wo[d] = oW1[row * HD + t];
      wsv[d] = sW1[row * HD + t];
    }
    for (int b = 0; b < BB; ++b) {
      float ao = 0.f, as = 0.f;
      #pragma unroll
      for (int d = 0; d < 16; ++d) {
        float f = lx[b * 16 + d];
        ao = fmaf(f, wo[d], ao);
        as = fmaf(f, wsv[d], as);
      }
      P_o[(b * SSLOT + s) * HD + t] = f2b(ao);
      P_s[(b * SSLOT + s) * HD + t] = f2b(as);
    }
  } else {
    const int v = wg - SSLOT;
    for (int i = t; i < BB * 16; i += 256) {
      int b = i >> 4, d = i & 15;
      lx[i] = xu[(b * UU + v) * 16 + d];
    }
    __syncthreads();
    float wo[16], wsv[16];
    #pragma unroll
    for (int d = 0; d < 16; ++d) {
      int row = SSLOT * 16 + v * 16 + d;
      wo[d] = oW1[row * HD + t];
      wsv[d] = sW1[row * HD + t];
    }
    for (int b = 0; b < BB; ++b) {
      float ao = 0.f, as = 0.f;
      #pragma unroll
      for (int d = 0; d < 16; ++d) {
        float f = lx[b * 16 + d];
        ao = fmaf(f, wo[d], ao);
        as = fmaf(f, wsv[d], as);
      }
      Q_o[(b * UU + v) * HD + t] = f2b(ao);
      Q_s[(b * UU + v) * HD + t] = f2b(as);
    }
  }
}

// ---------------------------------------------------------------------------
// K2: h1 = relu(b1 + sum connected P + sum connected Q). Vectorized:
// one user per 64-lane wave, lane owns 4 cols (uint2 = 4 bf16 per array).
// bf16->f32 expand via shift/mask (no v_cvt).
// ---------------------------------------------------------------------------
__global__ __launch_bounds__(256) void k_h1(
    const unsigned long long* __restrict__ connS,
    const unsigned long long* __restrict__ connU,
    const __hip_bfloat16* __restrict__ P_o, const __hip_bfloat16* __restrict__ P_s,
    const __hip_bfloat16* __restrict__ Q_o, const __hip_bfloat16* __restrict__ Q_s,
    const float* __restrict__ ob1, const float* __restrict__ sb1,
    __hip_bfloat16* __restrict__ h1o, __hip_bfloat16* __restrict__ h1s) {
  const int orig = blockIdx.x;                       // 4096 blocks
  const int blk = (orig & 7) * (4096 / 8) + (orig >> 3);  // XCD-affine chunks
  const int wid = threadIdx.x >> 6, lane = threadIdx.x & 63;
  const int u = blk * 4 + wid;
  const int b = u >> 8;
  const int c0 = lane * 4;
  float4 ao = *(const float4*)(ob1 + c0);
  float4 asv = *(const float4*)(sb1 + c0);
  const __hip_bfloat16* Pob = P_o + (size_t)b * SSLOT * HD + c0;
  const __hip_bfloat16* Psb = P_s + (size_t)b * SSLOT * HD + c0;
  unsigned long long ms = connS[u];
  while (ms) {
    int s = __ffsll(ms) - 1; ms &= ms - 1;
    uint2 vo = *(const uint2*)(Pob + s * HD);
    uint2 vs = *(const uint2*)(Psb + s * HD);
    ao.x += uf(vo.x << 16); ao.y += uf(vo.x & 0xFFFF0000u);
    ao.z += uf(vo.y << 16); ao.w += uf(vo.y & 0xFFFF0000u);
    asv.x += uf(vs.x << 16); asv.y += uf(vs.x & 0xFFFF0000u);
    asv.z += uf(vs.y << 16); asv.w += uf(vs.y & 0xFFFF0000u);
  }
  const __hip_bfloat16* Qob = Q_o + (size_t)b * UU * HD + c0;
  const __hip_bfloat16* Qsb = Q_s + (size_t)b * UU * HD + c0;
  #pragma unroll
  for (int w = 0; w < 4; ++w) {
    unsigned long long mu = connU[u * 4 + w];
    while (mu) {
      int v = (w << 6) + __ffsll(mu) - 1;
      mu &= mu - 1;
      uint2 vo = *(const uint2*)(Qob + v * HD);
      uint2 vs = *(const uint2*)(Qsb + v * HD);
      ao.x += uf(vo.x << 16); ao.y += uf(vo.x & 0xFFFF0000u);
      ao.z += uf(vo.y << 16); ao.w += uf(vo.y & 0xFFFF0000u);
      asv.x += uf(vs.x << 16); asv.y += uf(vs.x & 0xFFFF0000u);
      asv.z += uf(vs.y << 16); asv.w += uf(vs.y & 0xFFFF0000u);
    }
  }
  uint2 ro, rs;
  ro.x = pack2(fmaxf(ao.x, 0.f), fmaxf(ao.y, 0.f));
  ro.y = pack2(fmaxf(ao.z, 0.f), fmaxf(ao.w, 0.f));
  rs.x = pack2(fmaxf(asv.x, 0.f), fmaxf(asv.y, 0.f));
  rs.y = pack2(fmaxf(asv.z, 0.f), fmaxf(asv.w, 0.f));
  *(uint2*)(h1o + (size_t)u * HD + c0) = ro;
  *(uint2*)(h1s + (size_t)u * HD + c0) = rs;
}

// ---------------------------------------------------------------------------
// K3o: h2o = sigmoid(h1o @ W2o + b2) fused with offloading head + softmax2.
// M-tile 64, N=256 full, 4 waves (2x2), wave tile 32x128. h2o never leaves regs.
// ---------------------------------------------------------------------------
__global__ __launch_bounds__(256) void k_h2o(
    const __hip_bfloat16* __restrict__ h1o, const __hip_bfloat16* __restrict__ W2T_o,
    const float* __restrict__ ob2, const float* __restrict__ oW3,
    const float* __restrict__ ob3, float* __restrict__ out) {
  const int u0 = blockIdx.x * 64;
  const int t = threadIdx.x;
  const int lane = t & 63;
  const int wid = t >> 6;
  const int wr = wid >> 1, wc = wid & 1;
  __shared__ short As[64 * 64];
  __shared__ short Bs[256 * 64];
  __shared__ float part[2][64][2];
  f32x4 acc[2][8] = {};
  for (int kt = 0; kt < 4; ++kt) {
    const int kb = kt * 64;
    #pragma unroll
    for (int i = 0; i < 2; ++i) {                 // A: 512 chunks
      int c = t + i * 256;
      int row = c >> 3, cc = c & 7;
      *(short8*)&As[row * 64 + (cc ^ (row & 7)) * 8] =
          *(const short8*)(h1o + (size_t)(u0 + row) * HD + kb + cc * 8);
    }
    #pragma unroll
    for (int i = 0; i < 8; ++i) {                 // B: 2048 chunks
      int c = t + i * 256;
      int row = c >> 3, cc = c & 7;
      *(short8*)&Bs[row * 64 + (cc ^ (row & 7)) * 8] =
          *(const short8*)(W2T_o + (size_t)row * HD + kb + cc * 8);
    }
    __syncthreads();
    #pragma unroll
    for (int ks = 0; ks < 2; ++ks) {
      int c = ks * 4 + (lane >> 4);
      short8 af[2], bf[8];
      #pragma unroll
      for (int rb = 0; rb < 2; ++rb) {
        int row = wr * 32 + rb * 16 + (lane & 15);
        af[rb] = *(const short8*)&As[row * 64 + (c ^ (row & 7)) * 8];
      }
      #pragma unroll
      for (int cb = 0; cb < 8; ++cb) {
        int rn = wc * 128 + cb * 16 + (lane & 15);
        bf[cb] = *(const short8*)&Bs[rn * 64 + (c ^ (rn & 7)) * 8];
      }
      #pragma unroll
      for (int rb = 0; rb < 2; ++rb)
        #pragma unroll
        for (int cb = 0; cb < 8; ++cb)
          acc[rb][cb] = __builtin_amdgcn_mfma_f32_16x16x32_bf16(af[rb], bf[cb], acc[rb][cb], 0, 0, 0);
    }
    __syncthreads();
  }
  // epilogue: sigmoid + dot with oW3[:,0:2], reduce, softmax2
  float p0[2][4] = {}, p1[2][4] = {};
  #pragma unroll
  for (int cb = 0; cb < 8; ++cb) {
    int n = wc * 128 + cb * 16 + (lane & 15);
    float bs = ob2[n], w0 = oW3[2 * n], w1 = oW3[2 * n + 1];
    #pragma unroll
    for (int rb = 0; rb < 2; ++rb)
      #pragma unroll
      for (int j = 0; j < 4; ++j) {
        float sig = 1.0f / (1.0f + __expf(-(acc[rb][cb][j] + bs)));
        p0[rb][j] = fmaf(sig, w0, p0[rb][j]);
        p1[rb][j] = fmaf(sig, w1, p1[rb][j]);
      }
  }
  #pragma unroll
  for (int rb = 0; rb < 2; ++rb)
    #pragma unroll
    for (int j = 0; j < 4; ++j) {
      #pragma unroll
      for (int off = 1; off < 16; off <<= 1) {
        p0[rb][j] += __shfl_xor(p0[rb][j], off, 64);
        p1[rb][j] += __shfl_xor(p1[rb][j], off, 64);
      }
      if ((lane & 15) == 0) {
        int ul = wr * 32 + rb * 16 + (lane >> 4) * 4 + j;
        part[wc][ul][0] = p0[rb][j];
        part[wc][ul][1] = p1[rb][j];
      }
    }
  __syncthreads();
  if (t < 64) {
    float q0 = part[0][t][0] + part[1][t][0] + ob3[0];
    float q1 = part[0][t][1] + part[1][t][1] + ob3[1];
    float m2 = fmaxf(q0, q1);
    float e0 = __expf(q0 - m2), e1 = __expf(q1 - m2);
    float iv = 1.0f / (e0 + e1);
    float2 r; r.x = e0 * iv; r.y = e1 * iv;
    *(float2*)(out + (size_t)(u0 + t) * 2) = r;
  }
}

// ---------------------------------------------------------------------------
// K3s: h2s = sigmoid(h1s @ W2s + b2) kept in LDS, fused sel GEMM (x sW3T)
// + masked softmax, writes selection probs directly.
// ---------------------------------------------------------------------------
#define SELP 264   // padded LDS row stride (shorts), 528B = 16B-aligned
__global__ __launch_bounds__(256) void k_h2s(
    const __hip_bfloat16* __restrict__ h1s, const __hip_bfloat16* __restrict__ W2T_s,
    const float* __restrict__ sb2, const __hip_bfloat16* __restrict__ W3T_s,
    const float* __restrict__ sb3, const unsigned long long* __restrict__ connS,
    float* __restrict__ out) {
  const int u0 = blockIdx.x * 64;
  const int t = threadIdx.x;
  const int lane = t & 63;
  const int wid = t >> 6;
  const int wr = wid >> 1, wc = wid & 1;
  __shared__ __align__(16) char lds[2 * SELP * 64 * 2];  // 67584 B
  short* As  = (short*)lds;            // 8 KB   (phase 1)
  short* Bs  = (short*)(lds + 8192);   // 32 KB  (phase 1)
  short* sel = (short*)lds;            // 64 x SELP (phase 2)
  short* w3  = (short*)(lds + SELP * 64 * 2);  // 64 x SELP (phase 2)
  f32x4 acc[2][8] = {};
  for (int kt = 0; kt < 4; ++kt) {
    const int kb = kt * 64;
    #pragma unroll
    for (int i = 0; i < 2; ++i) {
      int c = t + i * 256;
      int row = c >> 3, cc = c & 7;
      *(short8*)&As[row * 64 + (cc ^ (row & 7)) * 8] =
          *(const short8*)(h1s + (size_t)(u0 + row) * HD + kb + cc * 8);
    }
    #pragma unroll
    for (int i = 0; i < 8; ++i) {
      int c = t + i * 256;
      int row = c >> 3, cc = c & 7;
      *(short8*)&Bs[row * 64 + (cc ^ (row & 7)) * 8] =
          *(const short8*)(W2T_s + (size_t)row * HD + kb + cc * 8);
    }
    __syncthreads();
    #pragma unroll
    for (int ks = 0; ks < 2; ++ks) {
      int c = ks * 4 + (lane >> 4);
      short8 af[2], bf[8];
      #pragma unroll
      for (int rb = 0; rb < 2; ++rb) {
        int row = wr * 32 + rb * 16 + (lane & 15);
        af[rb] = *(const short8*)&As[row * 64 + (c ^ (row & 7)) * 8];
      }
      #pragma unroll
      for (int cb = 0; cb < 8; ++cb) {
        int rn = wc * 128 + cb * 16 + (lane & 15);
        bf[cb] = *(const short8*)&Bs[rn * 64 + (c ^ (rn & 7)) * 8];
      }
      #pragma unroll
      for (int rb = 0; rb < 2; ++rb)
        #pragma unroll
        for (int cb = 0; cb < 8; ++cb)
          acc[rb][cb] = __builtin_amdgcn_mfma_f32_16x16x32_bf16(af[rb], bf[cb], acc[rb][cb], 0, 0, 0);
    }
    __syncthreads();
  }
  // phase 2a: sigmoid -> sel LDS (bf16), stage W3T into LDS
  #pragma unroll
  for (int cb = 0; cb < 8; ++cb) {
    int n = wc * 128 + cb * 16 + (lane & 15);
    float bs = sb2[n];
    #pragma unroll
    for (int rb = 0; rb < 2; ++rb)
      #pragma unroll
      for (int j = 0; j < 4; ++j) {
        int ul = wr * 32 + rb * 16 + (lane >> 4) * 4 + j;
        float sig = 1.0f / (1.0f + __expf(-(acc[rb][cb][j] + bs)));
        sel[ul * SELP + n] = (short)pack2(sig, 0.f);  // low half = bf16(sig)
      }
  }
  #pragma unroll
  for (int i = 0; i < 8; ++i) {                  // w3: 64 rows x 32 chunks
    int c = t + i * 256;
    int row = c >> 5, cc = c & 31;
    *(short8*)&w3[row * SELP + cc * 8] =
        *(const short8*)(W3T_s + (size_t)row * HD + cc * 8);
  }
  __syncthreads();
  // phase 2b: lg = sel @ w3^T ; wave tile 16 users x 64 cols
  f32x4 acc2[4] = {};
  #pragma unroll
  for (int ks = 0; ks < 8; ++ks) {
    int c = ks * 4 + (lane >> 4);
    int row = wid * 16 + (lane & 15);
    short8 af = *(const short8*)&sel[row * SELP + c * 8];
    #pragma unroll
    for (int cb = 0; cb < 4; ++cb) {
      int rn = cb * 16 + (lane & 15);
      short8 bf = *(const short8*)&w3[rn * SELP + c * 8];
      acc2[cb] = __builtin_amdgcn_mfma_f32_16x16x32_bf16(af, bf, acc2[cb], 0, 0, 0);
    }
  }
  // phase 2c: masked softmax over 64 slots, write out
  float sb3n[4];
  #pragma unroll
  for (int cb = 0; cb < 4; ++cb) sb3n[cb] = sb3[cb * 16 + (lane & 15)];
  const int ubase = u0 + wid * 16 + (lane >> 4) * 4;
  #pragma unroll
  for (int j = 0; j < 4; ++j) {
    unsigned long long m = connS[ubase + j];
    float v[4]; bool ok[4];
    float mx = -INFINITY;
    #pragma unroll
    for (int cb = 0; cb < 4; ++cb) {
      int n = cb * 16 + (lane & 15);
      ok[cb] = (m >> n) & 1ull;
      v[cb] = ok[cb] ? (acc2[cb][j] + sb3n[cb]) : -INFINITY;
      mx = fmaxf(mx, v[cb]);
    }
    #pragma unroll
    for (int off = 1; off < 16; off <<= 1) mx = fmaxf(mx, __shfl_xor(mx, off, 64));
    float e[4], ssum = 0.f;
    #pragma unroll
    for (int cb = 0; cb < 4; ++cb) {
      e[cb] = ok[cb] ? __expf(v[cb] - mx) : 0.f;
      ssum += e[cb];
    }
    #pragma unroll
    for (int off = 1; off < 16; off <<= 1) ssum += __shfl_xor(ssum, off, 64);
    float iv = 1.0f / ssum;
    #pragma unroll
    for (int cb = 0; cb < 4; ++cb) {
      int n = cb * 16 + (lane & 15);
      out[(size_t)NUSER * 2 + (size_t)(ubase + j) * SSLOT + n] = e[cb] * iv;
    }
  }
}

// ---------------------------------------------------------------------------
extern "C" void kernel_launch(void* const* d_in, const int* in_sizes, int n_in,
                              void* d_out, int out_size, void* d_ws, size_t ws_size,
                              hipStream_t stream) {
  const float* x_user   = (const float*)d_in[0];
  const float* x_server = (const float*)d_in[1];
  const int*   dst_u2s  = (const int*)d_in[3];
  const int*   dst_u2u  = (const int*)d_in[5];
  const float* oW1 = (const float*)d_in[6];
  const float* ob1 = (const float*)d_in[7];
  const float* oW2 = (const float*)d_in[8];
  const float* ob2 = (const float*)d_in[9];
  const float* oW3 = (const float*)d_in[10];
  const float* ob3 = (const float*)d_in[11];
  const float* sW1 = (const float*)d_in[12];
  const float* sb1 = (const float*)d_in[13];
  const float* sW2 = (const float*)d_in[14];
  const float* sb2 = (const float*)d_in[15];
  const float* sW3 = (const float*)d_in[16];
  const float* sb3 = (const float*)d_in[17];

  char* ws = (char*)d_ws;
  unsigned long long* connS = (unsigned long long*)(ws + 0);         // 128 KB
  unsigned long long* connU = (unsigned long long*)(ws + 131072);    // 512 KB
  __hip_bfloat16* P_o  = (__hip_bfloat16*)(ws + 655360);             // 2 MB
  __hip_bfloat16* P_s  = (__hip_bfloat16*)(ws + 2752512);            // 2 MB
  __hip_bfloat16* Q_o  = (__hip_bfloat16*)(ws + 4849664);            // 8 MB
  __hip_bfloat16* Q_s  = (__hip_bfloat16*)(ws + 13238272);           // 8 MB
  __hip_bfloat16* h1o  = (__hip_bfloat16*)(ws + 21626880);           // 8 MB
  __hip_bfloat16* h1s  = (__hip_bfloat16*)(ws + 30015488);           // 8 MB
  __hip_bfloat16* W2T_o = (__hip_bfloat16*)(ws + 38404096);          // 128 KB
  __hip_bfloat16* W2T_s = (__hip_bfloat16*)(ws + 38535168);          // 128 KB
  __hip_bfloat16* W3T_s = (__hip_bfloat16*)(ws + 38666240);          // 32 KB
  float* out = (float*)d_out;

  k_setup<<<256, 256, 0, stream>>>(dst_u2s, dst_u2u, oW2, sW2, sW3,
                                   connS, connU, W2T_o, W2T_s, W3T_s);
  k_pq<<<SSLOT + UU, 256, 0, stream>>>(x_user, x_server, oW1, sW1, P_o, P_s, Q_o, Q_s);
  k_h1<<<NUSER / 4, 256, 0, stream>>>(connS, connU, P_o, P_s, Q_o, Q_s, ob1, sb1, h1o, h1s);
  k_h2o<<<NUSER / 64, 256, 0, stream>>>(h1o, W2T_o, ob2, oW3, ob3, out);
  k_h2s<<<NUSER / 64, 256, 0, stream>>>(h1s, W2T_s, sb2, W3T_s, sb3, connS, out);
}